// Round 11
// baseline (201.538 us; speedup 1.0000x reference)
//
#include <hip/hip_runtime.h>
#include <hip/hip_bf16.h>

typedef short bf16x8 __attribute__((ext_vector_type(8)));
typedef short bf16x4 __attribute__((ext_vector_type(4)));
typedef float f32x4 __attribute__((ext_vector_type(4)));
typedef unsigned short u16x8 __attribute__((ext_vector_type(8)));
typedef unsigned short u16x4 __attribute__((ext_vector_type(4)));

#define DEV static __device__ __forceinline__

DEV unsigned short f2bf(float f) {
  unsigned int u = __builtin_bit_cast(unsigned int, f);
  u += 0x7FFFu + ((u >> 16) & 1u);   // round-to-nearest-even
  return (unsigned short)(u >> 16);
}
DEV float bf2f(unsigned short u) {
  return __builtin_bit_cast(float, (unsigned int)u << 16);
}

DEV void gload_lds16(const unsigned short* g, unsigned short* l) {
  __builtin_amdgcn_global_load_lds(
      (const __attribute__((address_space(1))) unsigned int*)g,
      (__attribute__((address_space(3))) unsigned int*)l, 16, 0, 0);
}

DEV void waitv(int n) {   // n is compile-time under full unroll -> folds
  switch (n) {
    case 0: asm volatile("s_waitcnt vmcnt(0)" ::: "memory"); break;
    case 1: asm volatile("s_waitcnt vmcnt(1)" ::: "memory"); break;
    case 2: asm volatile("s_waitcnt vmcnt(2)" ::: "memory"); break;
    case 3: asm volatile("s_waitcnt vmcnt(3)" ::: "memory"); break;
    case 4: asm volatile("s_waitcnt vmcnt(4)" ::: "memory"); break;
    case 5: asm volatile("s_waitcnt vmcnt(5)" ::: "memory"); break;
    case 6: asm volatile("s_waitcnt vmcnt(6)" ::: "memory"); break;
    default: asm volatile("s_waitcnt vmcnt(0)" ::: "memory"); break;
  }
}

#define SB() __builtin_amdgcn_sched_barrier(0)
#define BAR() do { __builtin_amdgcn_s_barrier(); SB(); } while (0)
#define LBAR() do { asm volatile("s_waitcnt lgkmcnt(0)" ::: "memory"); \
                    SB(); \
                    __builtin_amdgcn_s_barrier(); \
                    SB(); } while (0)
#define WAITL() do { asm volatile("s_waitcnt lgkmcnt(0)" ::: "memory"); SB(); } while (0)
#define PRIO1() __builtin_amdgcn_s_setprio(1)
#define PRIO0() __builtin_amdgcn_s_setprio(0)

DEV void amask(unsigned mwv, f32x4& s) {
  if (mwv) {
#pragma unroll
    for (int r = 0; r < 4; ++r)
      if ((mwv >> (8 * r)) & 0xffu) s[r] = -1.0e30f;
  }
}

// ---------------------------------------------------------------------------
// Convert pass: f32 -> bf16 for q,k,v (4M elems each) and Wq,Wk,Wv (1M each).
// ---------------------------------------------------------------------------
__global__ __launch_bounds__(256) void cvt_kernel(
    const float* __restrict__ q, const float* __restrict__ k,
    const float* __restrict__ v, const float* __restrict__ wq,
    const float* __restrict__ wk, const float* __restrict__ wv,
    unsigned short* __restrict__ xq, unsigned short* __restrict__ xk,
    unsigned short* __restrict__ xv, unsigned short* __restrict__ wqb,
    unsigned short* __restrict__ wkb, unsigned short* __restrict__ wvb)
{
  int tid = blockIdx.x * 256 + threadIdx.x;
  const float* src; unsigned short* dst; int off;
  if      (tid <  524288) { src = q;  dst = xq;  off = tid; }
  else if (tid < 1048576) { src = k;  dst = xk;  off = tid -  524288; }
  else if (tid < 1572864) { src = v;  dst = xv;  off = tid - 1048576; }
  else if (tid < 1703936) { src = wq; dst = wqb; off = tid - 1572864; }
  else if (tid < 1835008) { src = wk; dst = wkb; off = tid - 1703936; }
  else                    { src = wv; dst = wvb; off = tid - 1835008; }
  size_t e = (size_t)off * 8;
  float4 a = *(const float4*)(src + e);
  float4 b = *(const float4*)(src + e + 4);
  u16x8 p = { f2bf(a.x), f2bf(a.y), f2bf(a.z), f2bf(a.w),
              f2bf(b.x), f2bf(b.y), f2bf(b.z), f2bf(b.w) };
  *(u16x8*)(dst + e) = p;
}

// ---------------------------------------------------------------------------
// Fused projection GEMMs (unchanged from r10): 128x128 tile, BK=64, 8 waves,
// global_load_lds 2-slot double buffer, both-sides XOR swizzle, XCD swizzle.
// ---------------------------------------------------------------------------
__global__ __launch_bounds__(512, 2) void gemm_kernel(
    const unsigned short* __restrict__ xq, const unsigned short* __restrict__ xk,
    const unsigned short* __restrict__ xv, const unsigned short* __restrict__ wqb,
    const unsigned short* __restrict__ wkb, const unsigned short* __restrict__ wvb,
    const float* __restrict__ bq, const float* __restrict__ bk,
    const float* __restrict__ bv, unsigned short* __restrict__ qp,
    unsigned short* __restrict__ kp, unsigned short* __restrict__ vt)
{
  __shared__ union {
    unsigned short ab[2][2][128][64];   // [buf][A=0/B=1][row][unit*8]
    unsigned short T[128][132];         // V-transpose epilogue (+4 pad)
  } smu;
  const int t = threadIdx.x, lane = t & 63, wv8 = t >> 6;
  const int ln = lane & 15, g = lane >> 4;
  const int wm2 = wv8 >> 2, wn4 = wv8 & 3;
  const int seg = blockIdx.x >> 8, lb = blockIdx.x & 255;
  const int x8 = lb & 7, s32 = lb >> 3;
  const int m0 = (x8 * 4 + (s32 >> 3)) * 128;   // same-m blocks share an XCD
  const int n0 = (s32 & 7) * 128;

  const unsigned short* X; const unsigned short* W; const float* bias;
  unsigned short* outR; int mode;
  if (seg == 0)      { X = xq; W = wqb; bias = bq; outR = qp; mode = 0; }
  else if (seg == 1) { X = xk; W = wkb; bias = bk; outR = kp; mode = 0; }
  else               { X = xv; W = wvb; bias = bv; outR = vt; mode = 2; }

  f32x4 acc[4][2];
#pragma unroll
  for (int i = 0; i < 4; ++i)
#pragma unroll
    for (int j = 0; j < 2; ++j) acc[i][j] = {0.f, 0.f, 0.f, 0.f};

  const int lrow = lane >> 3;                     // 0..7
  const int lcol = ((lane & 7) ^ lrow) * 8;       // pre-swizzled source unit

#define STAGE_G(kt) do { \
    const int _k0 = (kt) * 64; \
    _Pragma("unroll") \
    for (int i = 0; i < 2; ++i) { \
      const int r = wv8 * 16 + i * 8; \
      gload_lds16(X + (size_t)(m0 + r + lrow) * 1024 + _k0 + lcol, \
                  &smu.ab[(kt) & 1][0][r][0]); \
      gload_lds16(W + (size_t)(n0 + r + lrow) * 1024 + _k0 + lcol, \
                  &smu.ab[(kt) & 1][1][r][0]); \
    } } while (0)

  STAGE_G(0);
  waitv(0);
  BAR();
#pragma unroll 2
  for (int kt = 0; kt < 16; ++kt) {
    if (kt < 15) STAGE_G(kt + 1);
    SB();
#pragma unroll
    for (int ks = 0; ks < 2; ++ks) {
      bf16x8 af[4], bfr[2];
      const int ru = ((ks * 4 + g) ^ (ln & 7)) * 8;   // swizzled read unit
#pragma unroll
      for (int i = 0; i < 4; ++i)
        af[i] = *(const bf16x8*)&smu.ab[kt & 1][0][wm2 * 64 + i * 16 + ln][ru];
#pragma unroll
      for (int j = 0; j < 2; ++j)
        bfr[j] = *(const bf16x8*)&smu.ab[kt & 1][1][wn4 * 32 + j * 16 + ln][ru];
      PRIO1();
#pragma unroll
      for (int i = 0; i < 4; ++i)
#pragma unroll
        for (int j = 0; j < 2; ++j)
          acc[i][j] = __builtin_amdgcn_mfma_f32_16x16x32_bf16(
              af[i], bfr[j], acc[i][j], 0, 0, 0);
      PRIO0();
    }
    SB();
    waitv(0);            // next-tile DMAs landed (partially hidden by MFMA)
    BAR();
  }

  float bvv[2];
#pragma unroll
  for (int j = 0; j < 2; ++j) bvv[j] = bias[n0 + wn4 * 32 + j * 16 + ln];

  if (mode == 0) {
#pragma unroll
    for (int i = 0; i < 4; ++i)
#pragma unroll
      for (int j = 0; j < 2; ++j)
#pragma unroll
        for (int r = 0; r < 4; ++r) {
          int row = m0 + wm2 * 64 + i * 16 + g * 4 + r;
          int col = n0 + wn4 * 32 + j * 16 + ln;
          outR[(size_t)row * 1024 + col] = f2bf(acc[i][j][r] + bvv[j]);
        }
  } else {
    __syncthreads();   // all fragment reads done; reuse LDS as T
#pragma unroll
    for (int i = 0; i < 4; ++i)
#pragma unroll
      for (int j = 0; j < 2; ++j)
#pragma unroll
        for (int r = 0; r < 4; ++r)
          smu.T[wn4 * 32 + j * 16 + ln][wm2 * 64 + i * 16 + g * 4 + r] =
              f2bf(acc[i][j][r] + bvv[j]);
    __syncthreads();
    const int bb = m0 >> 10, l0 = m0 & 1023;
#pragma unroll
    for (int it = 0; it < 4; ++it) {
      const int col = it * 32 + (t >> 4);
      const int r8 = (t & 15) * 8;
      *(u16x8*)&outR[((size_t)(bb * 16 + (n0 >> 6) + (col >> 6)) * 64 + (col & 63)) * 1024 + l0 + r8] =
          *(const u16x8*)&smu.T[col][r8];
    }
  }
#undef STAGE_G
}

// ---------------------------------------------------------------------------
// Attention v2: block = (b, h, 16 q-rows), 512 threads = 8 waves, wave w owns
// keys [w*128, w*128+128). Per-wave state: sc[8] (32 regs) -> <=64-reg class.
// QK: per-wave private 2-slot K ring, zero barriers, rolling 2-reg mask
// pipeline (recounted vmcnt {2,3,...,3,1}). PV: per-wave private 3-slot V
// ring ([64d][16k] chunks, conflict-free b64 reads), zero barriers, counted
// vmcnt {2,4,4,2} incl. interleaved attention stores. Only 3 block barriers
// total (softmax reduce, ctxp write, ctxp read). Residual qp+ctx -> d_out.
// ---------------------------------------------------------------------------
__global__ __launch_bounds__(512, 8) void attn_kernel(
    const unsigned short* __restrict__ qp, const unsigned short* __restrict__ kp,
    const unsigned short* __restrict__ vt, const unsigned char* __restrict__ masks,
    float* __restrict__ attn_out, float* __restrict__ res_out)
{
  __shared__ union {
    unsigned short Kw[8][2][1024];   // per-wave K rings: 2 x (16 keys x 64 d)
    unsigned short Vw[8][3][1024];   // per-wave V rings: 3 x (64 d x 16 k)
    float ctxp[8][16][68];           // reduction phase (+4 pad)
  } sm;
  __shared__ float red[2][16][8];    // [max/sum][ln][wave]

  const int t = threadIdx.x;
  const int wq = t >> 6, lane = t & 63;
  const int ln = lane & 15, g = lane >> 4;
  const int hw = blockIdx.x;
  const int lid = (hw & 7) * 512 + (hw >> 3);  // cluster same-(b,h) per XCD
  const int b = lid >> 10, h = (lid >> 6) & 15, m0 = (lid & 63) * 16;
  const size_t rowbase = (size_t)(b * 1024 + m0);

  // ---- Q fragments (oldest vmcnt entries; retired by the first QK wait) ----
  bf16x8 qf[2];
  {
    const unsigned short* qb = qp + (rowbase + ln) * 1024 + h * 64 + g * 8;
    qf[0] = *(const bf16x8*)qb;
    qf[1] = *(const bf16x8*)(qb + 32);
  }
  SB();

  // staging geometry
  const int slr8 = lane >> 3;                // 0..7 local key row (K chunks)
  const int suK = (lane & 7) ^ slr8;         // swizzled K source unit
  const int vdr = lane >> 1;                 // 0..31 local d row (V chunks)
  const int vk8 = (lane & 1) * 8;            // k-offset within chunk
  const unsigned short* kbase =
      kp + (size_t)b * 1048576 + h * 64 + (size_t)wq * 128 * 1024;
  const unsigned short* vtb =
      vt + ((size_t)(b * 16 + h) * 64) * 1024 + wq * 128;
  unsigned short* kwv = &sm.Kw[wq][0][0];
  unsigned short* vwv = &sm.Vw[wq][0][0];
  const unsigned char* mrow =
      masks + ((size_t)b * 1024 + m0 + ln) * 1024 + wq * 128 + g * 4;

#define STAGE_K(s) do { \
    gload_lds16(kbase + (size_t)((s) * 16 + slr8) * 1024 + suK * 8, \
                kwv + ((s) & 1) * 1024); \
    gload_lds16(kbase + (size_t)((s) * 16 + 8 + slr8) * 1024 + suK * 8, \
                kwv + ((s) & 1) * 1024 + 512); } while (0)
#define STAGE_V(s) do { \
    gload_lds16(vtb + (size_t)vdr * 1024 + (s) * 16 + vk8, \
                vwv + ((s) % 3) * 1024); \
    gload_lds16(vtb + (size_t)(32 + vdr) * 1024 + (s) * 16 + vk8, \
                vwv + ((s) % 3) * 1024 + 512); } while (0)

  f32x4 sc[8];
#pragma unroll
  for (int i = 0; i < 8; ++i) sc[i] = {0.f, 0.f, 0.f, 0.f};

  // ---- QK^T: per-wave 2-slot ring, NO barriers, rolling mask pipeline ----
  STAGE_K(0); STAGE_K(1);
  SB();
  unsigned mq[2];
#pragma unroll
  for (int s = 0; s < 8; ++s) {
    waitv(s == 0 ? 2 : (s == 7 ? 1 : 3));
    SB();
    const unsigned short* ksl = kwv + (s & 1) * 1024 + ln * 64;
    bf16x8 kf0 = *(const bf16x8*)(ksl + (g ^ (ln & 7)) * 8);
    bf16x8 kf1 = *(const bf16x8*)(ksl + ((4 + g) ^ (ln & 7)) * 8);
    WAITL();                       // fragments in VGPRs; slot s&1 reusable
    if (s + 2 < 8) STAGE_K(s + 2);
    SB();
    if (s >= 2) amask(mq[s & 1], sc[s - 2]);   // m(s-2) retired by waitv
    mq[s & 1] = *(const unsigned*)(mrow + s * 16);
    PRIO1();
    sc[s] = __builtin_amdgcn_mfma_f32_16x16x32_bf16(kf0, qf[0], sc[s], 0, 0, 0);
    sc[s] = __builtin_amdgcn_mfma_f32_16x16x32_bf16(kf1, qf[1], sc[s], 0, 0, 0);
    PRIO0();
  }
  waitv(0);
  SB();
  amask(mq[0], sc[6]);
  amask(mq[1], sc[7]);

  // ---- softmax: wave-local max + local-max partial sum, ONE barrier ----
  const float C = 0.18033688011112042f;   // 0.125 * log2(e)
  float mx = -3.0e30f;
#pragma unroll
  for (int s = 0; s < 8; ++s)
#pragma unroll
    for (int r = 0; r < 4; ++r) mx = fmaxf(mx, sc[s][r]);
  mx = fmaxf(mx, __shfl_xor(mx, 16));
  mx = fmaxf(mx, __shfl_xor(mx, 32));     // wave's row max over its 128 keys
  const float mtl = mx * C;
  float sum = 0.f;
#pragma unroll
  for (int s = 0; s < 8; ++s)
#pragma unroll
    for (int r = 0; r < 4; ++r)
      sum += exp2f(__builtin_fmaf(sc[s][r], C, -mtl));
  sum += __shfl_xor(sum, 16);
  sum += __shfl_xor(sum, 32);
  if (g == 0) { red[0][ln][wq] = mx; red[1][ln][wq] = sum; }
  LBAR();                       // barrier #1: red ready AND all waves past QK

  STAGE_V(0); STAGE_V(1); STAGE_V(2);   // V latency hides under combine+exp
  SB();

  float m4 = red[0][ln][0];
#pragma unroll
  for (int i = 1; i < 8; ++i) m4 = fmaxf(m4, red[0][ln][i]);
  float l4 = 0.f;
#pragma unroll
  for (int i = 0; i < 8; ++i)
    l4 += red[1][ln][i] * exp2f((red[0][ln][i] - m4) * C);
  // P = exp2(s*C + beta), beta folds global max AND normalization
  const float beta = __builtin_fmaf(-m4, C, -__builtin_log2f(l4));

  // ---- normalized bf16 P fragments (also the attention output values) ----
  bf16x8 af[4];
#pragma unroll
  for (int c = 0; c < 4; ++c) {
    bf16x8 a;
#pragma unroll
    for (int r = 0; r < 4; ++r)
      a[r] = (short)f2bf(exp2f(__builtin_fmaf(sc[2 * c][r], C, beta)));
#pragma unroll
    for (int r = 0; r < 4; ++r)
      a[4 + r] = (short)f2bf(exp2f(__builtin_fmaf(sc[2 * c + 1][r], C, beta)));
    af[c] = a;
  }

  // ---- PV: per-wave 3-slot V ring, NO barriers, interleaved stores ----
  // per pair p: chunks 2p, 2p+1. vmcnt counts incl. stores: {2,4,4,2}.
  f32x4 cacc[4];
#pragma unroll
  for (int i = 0; i < 4; ++i) cacc[i] = {0.f, 0.f, 0.f, 0.f};
  const size_t abase =
      ((size_t)(b * 16 + h) * 1024 + (m0 + ln)) * 1024 + wq * 128 + g * 4;
#pragma unroll
  for (int p = 0; p < 4; ++p) {
    waitv(p == 0 ? 2 : (p == 3 ? 2 : 4));
    SB();
    bf16x4 b0[4], b1[4];
#pragma unroll
    for (int ni = 0; ni < 4; ++ni) {
      const int d = ni * 16 + ln;
      b0[ni] = *(const bf16x4*)(vwv + ((2 * p) % 3) * 1024 + d * 16 + g * 4);
      b1[ni] = *(const bf16x4*)(vwv + ((2 * p + 1) % 3) * 1024 + d * 16 + g * 4);
    }
    WAITL();                       // frags in VGPRs; pair's slots reusable
    if (p == 0)      { STAGE_V(3); STAGE_V(4); }
    else if (p == 1) { STAGE_V(5); STAGE_V(6); }
    else if (p == 2) { STAGE_V(7); }
    SB();
    PRIO1();
#pragma unroll
    for (int ni = 0; ni < 4; ++ni) {
      bf16x8 bfr = { b0[ni][0], b0[ni][1], b0[ni][2], b0[ni][3],
                     b1[ni][0], b1[ni][1], b1[ni][2], b1[ni][3] };
      cacc[ni] = __builtin_amdgcn_mfma_f32_16x16x32_bf16(af[p], bfr, cacc[ni], 0, 0, 0);
    }
    PRIO0();
    SB();
#pragma unroll
    for (int hf = 0; hf < 2; ++hf) {
      f32x4 v = { bf2f((unsigned short)af[p][hf * 4 + 0]),
                  bf2f((unsigned short)af[p][hf * 4 + 1]),
                  bf2f((unsigned short)af[p][hf * 4 + 2]),
                  bf2f((unsigned short)af[p][hf * 4 + 3]) };
      *(f32x4*)(attn_out + abase + p * 32 + hf * 16) = v;
    }
    SB();
  }

  // ---- cross-wave ctx reduction + residual -> d_out ----
  LBAR();                       // barrier #2: all Vw reads done; reuse as ctxp
#pragma unroll
  for (int ni = 0; ni < 4; ++ni)
#pragma unroll
    for (int r = 0; r < 4; ++r)
      sm.ctxp[wq][g * 4 + r][ni * 16 + ln] = cacc[ni][r];
  LBAR();                       // barrier #3
  if (t < 256) {
    const int m = t >> 4, d4 = (t & 15) * 4;
    f32x4 s = *(const f32x4*)&sm.ctxp[0][m][d4];
#pragma unroll
    for (int w = 1; w < 8; ++w) s += *(const f32x4*)&sm.ctxp[w][m][d4];
    const unsigned short* qrow = qp + (rowbase + m) * 1024 + h * 64 + d4;
    u16x4 qv = *(const u16x4*)qrow;
    f32x4 qf32 = { bf2f(qv[0]), bf2f(qv[1]), bf2f(qv[2]), bf2f(qv[3]) };
    s = s + qf32;
    *(f32x4*)(res_out + (rowbase + m) * 1024 + h * 64 + d4) = s;
  }
#undef STAGE_K
#undef STAGE_V
}

// ---------------------------------------------------------------------------
// In-place LayerNorm on d_out[:B*L*D]: out = LN(out) * g + b, one block/row.
// ---------------------------------------------------------------------------
__global__ __launch_bounds__(256) void ln_kernel(
    float* __restrict__ io,
    const float* __restrict__ gma, const float* __restrict__ bta)
{
  __shared__ float rbuf[2][4];
  const int r = blockIdx.x, t = threadIdx.x;
  const int i4 = t * 4;
  const size_t base = (size_t)r * 1024 + i4;
  f32x4 x = *(const f32x4*)(io + base);
  float s = x[0] + x[1] + x[2] + x[3];
  float q = x[0]*x[0] + x[1]*x[1] + x[2]*x[2] + x[3]*x[3];
#pragma unroll
  for (int off = 1; off < 64; off <<= 1) {
    s += __shfl_xor(s, off);
    q += __shfl_xor(q, off);
  }
  const int wv = t >> 6;
  if ((t & 63) == 0) { rbuf[0][wv] = s; rbuf[1][wv] = q; }
  __syncthreads();
  s = rbuf[0][0] + rbuf[0][1] + rbuf[0][2] + rbuf[0][3];
  q = rbuf[1][0] + rbuf[1][1] + rbuf[1][2] + rbuf[1][3];
  float mu = s * (1.0f / 1024.0f);
  float var = q * (1.0f / 1024.0f) - mu * mu;
  float is = rsqrtf(var + 1e-6f);
  f32x4 gv = *(const f32x4*)(gma + i4);
  f32x4 bv = *(const f32x4*)(bta + i4);
  f32x4 o;
#pragma unroll
  for (int k = 0; k < 4; ++k) o[k] = (x[k] - mu) * is * gv[k] + bv[k];
  *(f32x4*)(io + base) = o;
}

// ---------------------------------------------------------------------------
extern "C" void kernel_launch(void* const* d_in, const int* in_sizes, int n_in,
                              void* d_out, int out_size, void* d_ws, size_t ws_size,
                              hipStream_t stream) {
  const float* q  = (const float*)d_in[0];
  const float* k  = (const float*)d_in[1];
  const float* v  = (const float*)d_in[2];
  const unsigned char* masks = (const unsigned char*)d_in[3];
  const float* Wq = (const float*)d_in[4];
  const float* bq = (const float*)d_in[5];
  const float* Wk = (const float*)d_in[6];
  const float* bk = (const float*)d_in[7];
  const float* Wv = (const float*)d_in[8];
  const float* bv = (const float*)d_in[9];
  const float* lg = (const float*)d_in[10];
  const float* lb = (const float*)d_in[11];

  float* out = (float*)d_out;
  float* attn_out = out + (size_t)4 * 1024 * 1024;

  // bf16 input scratch lives in the attn region of d_out (overwritten later
  // by attn_kernel -- all reads happen in cvt/gemm, stream-ordered before).
  unsigned short* xq  = (unsigned short*)attn_out;
  unsigned short* xk  = xq + 4194304;
  unsigned short* xv  = xk + 4194304;
  unsigned short* wqb = xv + 4194304;
  unsigned short* wkb = wqb + 1048576;
  unsigned short* wvb = wkb + 1048576;

  // workspace: 24 MB (qp | kp | vt, all bf16 4M elems each)
  unsigned short* qp = (unsigned short*)d_ws;
  unsigned short* kp = qp + 4194304;
  unsigned short* vt = kp + 4194304;

  hipLaunchKernelGGL(cvt_kernel, dim3(7680), dim3(256), 0, stream,
                     q, k, v, Wq, Wk, Wv, xq, xk, xv, wqb, wkb, wvb);
  hipLaunchKernelGGL(gemm_kernel, dim3(768), dim3(512), 0, stream,
                     xq, xk, xv, wqb, wkb, wvb, bq, bk, bv, qp, kp, vt);
  hipLaunchKernelGGL(attn_kernel, dim3(4096), dim3(512), 0, stream,
                     qp, kp, vt, masks, attn_out, out);
  hipLaunchKernelGGL(ln_kernel, dim3(4096), dim3(256), 0, stream,
                     out, lg, lb);
}